// Round 1
// 465.284 us; speedup vs baseline: 1.3171x; 1.3171x over previous
//
#include <hip/hip_runtime.h>

typedef __attribute__((ext_vector_type(8))) short bf16x8;
typedef __attribute__((ext_vector_type(4))) short bf16x4;
typedef __attribute__((ext_vector_type(4))) float f32x4;

#define BATCH 2
#define CH    512
#define NPIX  4096

__device__ __forceinline__ unsigned short f2b(float f) {
    unsigned int u; __builtin_memcpy(&u, &f, 4);
    u = u + 0x7FFFu + ((u >> 16) & 1u);   // RNE
    return (unsigned short)(u >> 16);
}

// async 16B/lane global->LDS (wave-uniform LDS base, per-lane global src)
__device__ __forceinline__ void gll16(void* lds, const void* g) {
    __builtin_amdgcn_global_load_lds(
        (const __attribute__((address_space(1))) void*)g,
        (__attribute__((address_space(3))) void*)lds, 16, 0, 0);
}

// ---------------------------------------------------------------- fp32 -> bf16 weight convert
__global__ __launch_bounds__(256) void convert_kernel(
    const float* __restrict__ qkv_w, const float* __restrict__ proj_w,
    unsigned short* __restrict__ wbf)
{
    int i = blockIdx.x * 256 + threadIdx.x;            // grid covers 1048576
    float v = (i < 786432) ? qkv_w[i] : proj_w[i - 786432];
    wbf[i] = f2b(v);
}

// ---------------------------------------------------------------- GN stats
__global__ __launch_bounds__(256) void stats_kernel(
    const float* __restrict__ x, float* __restrict__ stats)
{
    int bg = blockIdx.x;           // 64 blocks: b*32+g
    int b = bg >> 5, g = bg & 31;
    const float* xp = x + ((size_t)b * CH + (size_t)g * 16) * NPIX;
    float s = 0.f, ss = 0.f;
    for (int i = threadIdx.x; i < 16 * NPIX; i += 256) {
        float v = xp[i]; s += v; ss += v * v;
    }
    for (int off = 32; off; off >>= 1) {
        s  += __shfl_down(s,  off, 64);
        ss += __shfl_down(ss, off, 64);
    }
    __shared__ float red[2][4];
    int wv = threadIdx.x >> 6;
    if ((threadIdx.x & 63) == 0) { red[0][wv] = s; red[1][wv] = ss; }
    __syncthreads();
    if (threadIdx.x == 0) {
        s  = red[0][0] + red[0][1] + red[0][2] + red[0][3];
        ss = red[1][0] + red[1][1] + red[1][2] + red[1][3];
        const float inv = 1.f / (16 * NPIX);
        float mean = s * inv;
        float var  = ss * inv - mean * mean;
        stats[bg * 2 + 0] = mean;
        stats[bg * 2 + 1] = rsqrtf(var + 1e-6f);
    }
}

// ---------------------------------------------------------------- K/V GEMM
// 512 threads (8 waves) for latency hiding; 32 pixels x ALL 1024 outputs.
__global__ __launch_bounds__(512) void kv_kernel(
    const float* __restrict__ x,
    const unsigned short* __restrict__ wbf,  // bf16 qkv_w [1536][512]
    const float* __restrict__ bias,
    const float* __restrict__ gamma,
    const float* __restrict__ beta,
    const float* __restrict__ stats,
    unsigned short* __restrict__ K,          // [b][n][c]
    unsigned short* __restrict__ V)          // [b][c][n]
{
    __shared__ unsigned short hn[32][520];
    int b  = blockIdx.y;
    int m0 = blockIdx.x * 32;
    int tid = threadIdx.x;
    {   // stage hn: p = tid&31 (pixel), cg = tid>>5 (channel slot, 16 wide)
        const float* xb = x + (size_t)b * CH * NPIX;
        const float* st = stats + b * 64;
        int p = tid & 31, cg = tid >> 5;
        for (int c0 = 0; c0 < CH; c0 += 16) {
            int c = c0 + cg;
            float mean = st[(c >> 4) * 2 + 0];
            float rstd = st[(c >> 4) * 2 + 1];
            float ga = gamma[c] * rstd;
            float be = beta[c] - mean * ga;
            hn[p][c] = f2b(xb[(size_t)c * NPIX + m0 + p] * ga + be);
        }
    }
    __syncthreads();

    int wv = tid >> 6, lane = tid & 63, ln = lane & 15, quad = lane >> 4;
    #pragma unroll
    for (int nt = 0; nt < 8; nt++) {
        int o = nt * 128 + wv * 16 + ln;           // [0, 1024)
        const unsigned short* bp = wbf + (size_t)(512 + o) * CH + quad * 8;
        bf16x8 wf[16];
        #pragma unroll
        for (int k = 0; k < 16; k++) wf[k] = *(const bf16x8*)(bp + k * 32);
        float bi = bias[512 + o];
        #pragma unroll
        for (int qt = 0; qt < 2; qt++) {
            f32x4 acc = {0.f, 0.f, 0.f, 0.f};
            #pragma unroll
            for (int k = 0; k < 16; k++) {
                bf16x8 a = *(const bf16x8*)(&hn[qt * 16 + ln][quad * 8 + k * 32]);
                acc = __builtin_amdgcn_mfma_f32_16x16x32_bf16(a, wf[k], acc, 0, 0, 0);
            }
            int m = m0 + qt * 16 + quad * 4;
            if (o < 512) {
                #pragma unroll
                for (int r = 0; r < 4; r++)
                    K[((size_t)b * NPIX + m + r) * CH + o] = f2b(acc[r] + bi);
            } else {
                bf16x4 pk;
                #pragma unroll
                for (int r = 0; r < 4; r++) pk[r] = f2b(acc[r] + bi);
                *(bf16x4*)(V + ((size_t)b * CH + o - 512) * NPIX + m) = pk;
            }
        }
    }
}

// ---------------------------------------------------------------- attention + proj
// 512 threads = 8 waves; 32 queries/block; 64-key tiles.
// K tiles double-buffered in LDS (async global_load_lds, XOR-swizzled source),
// raw s_barrier + counted vmcnt so the next tile's stage + this tile's V loads
// stay in flight across the whole iteration.
__global__ __launch_bounds__(512, 2) void attnproj_kernel(
    const float* __restrict__ x,
    const unsigned short* __restrict__ qw,   // bf16 qkv_w rows [0,512)
    const float* __restrict__ qb,
    const float* __restrict__ gamma,
    const float* __restrict__ beta,
    const float* __restrict__ stats,
    const unsigned short* __restrict__ Kg,
    const unsigned short* __restrict__ Vg,
    const unsigned short* __restrict__ pw,   // bf16 proj_w [512][512]
    const float* __restrict__ pb,
    float* __restrict__ out)
{
    // LDS map (bytes):
    //   [0,      65536)  K tile buf0 [64 rows][64 chunks of 16B], chunk c holds global chunk c^(row&7)
    //   [65536, 131072)  K tile buf1   (first written at iter 0 -> aliases below are safe)
    //   [65536,  98816)  hn / ao  [32][520] bf16   (live: start..PhaseQ ; again after flash loop)
    //   [98816, 132096)  qls      [32][520] bf16   (live: PhaseQ..qf preload; tail overlaps Sbuf)
    //   [131072,139776)  Sbuf [32][68] f32         (live: flash loop)
    //   [139776,144384)  Pbuf [32][72] bf16        (live: flash loop)
    __shared__ __align__(16) char sm[144384];
    char* const Kb0 = sm;
    char* const Kb1 = sm + 65536;
    unsigned short (*hn)[520]  = (unsigned short(*)[520])(sm + 65536);
    unsigned short (*qls)[520] = (unsigned short(*)[520])(sm + 98816);
    float (*Sbuf)[68]          = (float(*)[68])(sm + 131072);
    unsigned short (*Pbuf)[72] = (unsigned short(*)[72])(sm + 139776);
    __shared__ float mbuf[32], lbuf[32], abuf[32];

    int b  = blockIdx.y;
    int q0 = blockIdx.x * 32;
    int tid = threadIdx.x;
    int wv = tid >> 6, lane = tid & 63, ln = lane & 15, quad = lane >> 4;
    const float* xb = x + (size_t)b * CH * NPIX;
    const unsigned short* K = Kg + (size_t)b * NPIX * CH;
    const unsigned short* V = Vg + (size_t)b * CH * NPIX;

    {   // stage hn: p = tid&31 (pixel), cg = tid>>5 (channel slot, 16 wide)
        const float* st = stats + b * 64;
        int p = tid & 31, cg = tid >> 5;
        for (int c0 = 0; c0 < CH; c0 += 16) {
            int c = c0 + cg;
            float mean = st[(c >> 4) * 2 + 0];
            float rstd = st[(c >> 4) * 2 + 1];
            float ga = gamma[c] * rstd;
            float be = beta[c] - mean * ga;
            hn[p][c] = f2b(xb[(size_t)c * NPIX + q0 + p] * ga + be);
        }
    }
    if (tid < 32) { mbuf[tid] = -1e30f; lbuf[tid] = 0.f; }
    __syncthreads();

    // ---- prologue: async-stage K tile 0 into buf0 (hides under Phase Q;
    //      drained by Phase Q's __syncthreads which emits vmcnt(0))
    {
        const unsigned short* g = K + (size_t)wv * CH + ((lane ^ wv) << 3);
        char* l = Kb0 + wv * 1024;
        #pragma unroll
        for (int is = 0; is < 8; is++)
            gll16(l + is * 8192, g + (size_t)is * 8 * CH);
    }

    // ---- Phase Q: q[32][512]; wave wv computes channels [wv*64,+64)
    #pragma unroll
    for (int nt = 0; nt < 4; nt++) {
        int o = wv * 64 + nt * 16 + ln;
        const unsigned short* bp = qw + (size_t)o * CH + quad * 8;
        bf16x8 wf[16];
        #pragma unroll
        for (int k = 0; k < 16; k++) wf[k] = *(const bf16x8*)(bp + k * 32);
        float bi = qb[o];
        const float scale = 0.04419417382415922f;  // 512^-0.5
        #pragma unroll
        for (int qt = 0; qt < 2; qt++) {
            f32x4 acc = {0.f, 0.f, 0.f, 0.f};
            #pragma unroll
            for (int k = 0; k < 16; k++) {
                bf16x8 a = *(const bf16x8*)(&hn[qt * 16 + ln][quad * 8 + k * 32]);
                acc = __builtin_amdgcn_mfma_f32_16x16x32_bf16(a, wf[k], acc, 0, 0, 0);
            }
            #pragma unroll
            for (int r = 0; r < 4; r++)
                qls[qt * 16 + quad * 4 + r][o] = f2b((acc[r] + bi) * scale);
        }
    }
    __syncthreads();   // all waves: stage(0) complete here (compiler drains vmcnt)

    // ---- preload q fragments for this wave's S q-subtile
    int qs = wv >> 2, ks = wv & 3;
    bf16x8 qf[16];
    #pragma unroll
    for (int kt = 0; kt < 16; kt++)
        qf[kt] = *(const bf16x8*)(&qls[qs * 16 + ln][quad * 8 + kt * 32]);

    f32x4 O[2][4];   // [qt][ct], D[m=channel][n=query]
    #pragma unroll
    for (int qt = 0; qt < 2; qt++)
        #pragma unroll
        for (int ct = 0; ct < 4; ct++) O[qt][ct] = (f32x4){0.f, 0.f, 0.f, 0.f};

    int c0 = wv * 64;
    __syncthreads();   // qls dead after this point; K buf1 / Sbuf may be written

    const int key = ks * 16 + ln;     // key row within tile, this wave's S subtile
    const int swz = ln & 7;           // matches staging xor (row&7 == wv on write side)

    // ---- flash loop over 64-key tiles, 3 raw barriers / iter, no vmcnt(0)
    for (int it = 0; it < 64; ++it) {
        int kb = it << 6;
        const char* bufC = (it & 1) ? Kb1 : Kb0;
        char* bufN       = (it & 1) ? Kb0 : Kb1;

        // (a) V register loads for this tile — in flight until PV
        const unsigned short* vp = V + (size_t)(c0 + ln) * NPIX + kb + quad * 8;
        bf16x8 vf[4][2];
        #pragma unroll
        for (int ct = 0; ct < 4; ct++)
            #pragma unroll
            for (int half = 0; half < 2; half++)
                vf[ct][half] = *(const bf16x8*)(vp + (size_t)ct * 16 * NPIX + half * 32);

        // (b) async-stage next K tile (last iter wraps to tile 0: harmless dummy
        //     that keeps the vmcnt(16) accounting uniform)
        {
            int nkb = (kb + 64) & (NPIX - 1);
            const unsigned short* g = K + (size_t)(nkb + wv) * CH + ((lane ^ wv) << 3);
            char* l = bufN + wv * 1024;
            #pragma unroll
            for (int is = 0; is < 8; is++)
                gll16(l + is * 8192, g + (size_t)is * 8 * CH);
        }

        // (c) wait for current tile only: queue = [stage(cur) ≤8][V 8][stage(next) 8];
        //     vmcnt decrements oldest-first, so ≤16 outstanding ⟹ stage(cur) landed.
        asm volatile("s_waitcnt vmcnt(16)" ::: "memory");
        __builtin_amdgcn_s_barrier();

        // (d) S = q·kᵀ for this wave's 16x16 subtile; K frags from LDS (swizzled),
        //     two independent accumulator chains
        const char* kbase = bufC + key * 1024;
        f32x4 Sa = {0.f, 0.f, 0.f, 0.f}, Sb = {0.f, 0.f, 0.f, 0.f};
        #pragma unroll
        for (int kt = 0; kt < 16; kt += 2) {
            bf16x8 k0 = *(const bf16x8*)(kbase + ((((kt    ) * 4 + quad) ^ swz) << 4));
            bf16x8 k1 = *(const bf16x8*)(kbase + ((((kt + 1) * 4 + quad) ^ swz) << 4));
            Sa = __builtin_amdgcn_mfma_f32_16x16x32_bf16(qf[kt],     k0, Sa, 0, 0, 0);
            Sb = __builtin_amdgcn_mfma_f32_16x16x32_bf16(qf[kt + 1], k1, Sb, 0, 0, 0);
        }
        f32x4 S = Sa + Sb;
        #pragma unroll
        for (int r = 0; r < 4; r++) Sbuf[qs * 16 + quad * 4 + r][ks * 16 + ln] = S[r];

        asm volatile("s_waitcnt lgkmcnt(0)" ::: "memory");
        __builtin_amdgcn_s_barrier();

        // (f) online softmax: row r (query) by 16 threads, 4 keys each
        {
            int r = tid >> 4, j = tid & 15;
            f32x4 sv = *(const f32x4*)(&Sbuf[r][j * 4]);
            float mx = fmaxf(fmaxf(sv[0], sv[1]), fmaxf(sv[2], sv[3]));
            #pragma unroll
            for (int off = 1; off < 16; off <<= 1) mx = fmaxf(mx, __shfl_xor(mx, off, 64));
            float mprev = mbuf[r];
            float mnew  = fmaxf(mprev, mx);
            float alpha = __expf(mprev - mnew);
            float e0 = __expf(sv[0] - mnew), e1 = __expf(sv[1] - mnew);
            float e2 = __expf(sv[2] - mnew), e3 = __expf(sv[3] - mnew);
            bf16x4 pk = { (short)f2b(e0), (short)f2b(e1), (short)f2b(e2), (short)f2b(e3) };
            *(bf16x4*)(&Pbuf[r][j * 4]) = pk;
            float sum = e0 + e1 + e2 + e3;
            #pragma unroll
            for (int off = 1; off < 16; off <<= 1) sum += __shfl_xor(sum, off, 64);
            if (j == 0) { mbuf[r] = mnew; lbuf[r] = lbuf[r] * alpha + sum; abuf[r] = alpha; }
        }
        asm volatile("s_waitcnt lgkmcnt(0)" ::: "memory");
        __builtin_amdgcn_s_barrier();

        // (h) PV: A=v[channel][key], B=P[query][key]; D[channel][query]
        #pragma unroll
        for (int qt = 0; qt < 2; qt++) {
            float al = abuf[qt * 16 + ln];
            #pragma unroll
            for (int ct = 0; ct < 4; ct++) {
                #pragma unroll
                for (int r = 0; r < 4; r++) O[qt][ct][r] *= al;
            }
            #pragma unroll
            for (int half = 0; half < 2; half++) {
                bf16x8 pf = *(const bf16x8*)(&Pbuf[qt * 16 + ln][half * 32 + quad * 8]);
                #pragma unroll
                for (int ct = 0; ct < 4; ct++)
                    O[qt][ct] = __builtin_amdgcn_mfma_f32_16x16x32_bf16(vf[ct][half], pf, O[qt][ct], 0, 0, 0);
            }
        }
    }
    __syncthreads();   // full drain (incl. dummy stage); K bufs dead; region becomes ao

    // ---- ao[query][channel] into hn region
    #pragma unroll
    for (int qt = 0; qt < 2; qt++) {
        float linv = 1.f / lbuf[qt * 16 + ln];
        #pragma unroll
        for (int ct = 0; ct < 4; ct++) {
            #pragma unroll
            for (int r = 0; r < 4; r++)
                hn[qt * 16 + ln][c0 + ct * 16 + quad * 4 + r] = f2b(O[qt][ct][r] * linv);
        }
    }
    __syncthreads();

    // ---- Phase proj: out channels [wv*64,+64) + bias + residual (fp32)
    #pragma unroll
    for (int nt = 0; nt < 4; nt++) {
        int o = wv * 64 + nt * 16 + ln;
        const unsigned short* bp = pw + (size_t)o * CH + quad * 8;
        bf16x8 wf[16];
        #pragma unroll
        for (int k = 0; k < 16; k++) wf[k] = *(const bf16x8*)(bp + k * 32);
        float bi = pb[o];
        #pragma unroll
        for (int qt = 0; qt < 2; qt++) {
            f32x4 acc = {0.f, 0.f, 0.f, 0.f};
            #pragma unroll
            for (int k = 0; k < 16; k++) {
                bf16x8 a = *(const bf16x8*)(&hn[qt * 16 + ln][quad * 8 + k * 32]);
                acc = __builtin_amdgcn_mfma_f32_16x16x32_bf16(a, wf[k], acc, 0, 0, 0);
            }
            size_t base = ((size_t)b * CH + o) * NPIX + q0 + qt * 16 + quad * 4;
            f32x4 xin = *(const f32x4*)(x + base);
            f32x4 o4;
            #pragma unroll
            for (int r = 0; r < 4; r++) o4[r] = xin[r] + acc[r] + bi;
            *(f32x4*)(out + base) = o4;
        }
    }
}

// ----------------------------------------------------------------
extern "C" void kernel_launch(void* const* d_in, const int* in_sizes, int n_in,
                              void* d_out, int out_size, void* d_ws, size_t ws_size,
                              hipStream_t stream)
{
    const float* x      = (const float*)d_in[0];
    const float* gn_g   = (const float*)d_in[1];
    const float* gn_b   = (const float*)d_in[2];
    const float* qkv_w  = (const float*)d_in[3];
    const float* qkv_b  = (const float*)d_in[4];
    const float* proj_w = (const float*)d_in[5];
    const float* proj_b = (const float*)d_in[6];
    float* out = (float*)d_out;

    // Workspace: K 8MB | V 8MB | weights-bf16 2MB | stats 512B
    unsigned short* ws  = (unsigned short*)d_ws;
    unsigned short* Kb  = ws;                         // [2][4096][512] bf16
    unsigned short* Vb  = ws + 4u * 1024 * 1024;      // [2][512][4096] bf16
    unsigned short* wbf = ws + 8u * 1024 * 1024;      // qkv_w | proj_w, bf16
    unsigned short* wq  = wbf;
    unsigned short* wp  = wbf + 786432;
    float* stats = (float*)(ws + 9u * 1024 * 1024 + 256u * 1024);

    convert_kernel<<<dim3(1048576 / 256), 256, 0, stream>>>(qkv_w, proj_w, wbf);
    stats_kernel  <<<dim3(64), 256, 0, stream>>>(x, stats);
    kv_kernel     <<<dim3(NPIX / 32, BATCH), 512, 0, stream>>>(
        x, wbf, qkv_b, gn_g, gn_b, stats, Kb, Vb);
    attnproj_kernel<<<dim3(NPIX / 32, BATCH), 512, 0, stream>>>(
        x, wq, qkv_b, gn_g, gn_b, stats, Kb, Vb, wp, proj_b, out);
}

// Round 2
// 372.442 us; speedup vs baseline: 1.6454x; 1.2493x over previous
//
#include <hip/hip_runtime.h>

typedef __attribute__((ext_vector_type(8))) short bf16x8;
typedef __attribute__((ext_vector_type(4))) short bf16x4;
typedef __attribute__((ext_vector_type(4))) float f32x4;

#define BATCH 2
#define CH    512
#define NPIX  4096
#define SPK   2048   // keys per split

__device__ __forceinline__ unsigned short f2b(float f) {
    unsigned int u; __builtin_memcpy(&u, &f, 4);
    u = u + 0x7FFFu + ((u >> 16) & 1u);   // RNE
    return (unsigned short)(u >> 16);
}
__device__ __forceinline__ float b2f(unsigned short h) {
    unsigned int u = ((unsigned int)h) << 16;
    float f; __builtin_memcpy(&f, &u, 4);
    return f;
}
// async 16B/lane global->LDS (wave-uniform LDS base, per-lane global src)
__device__ __forceinline__ void gll16(void* lds, const void* g) {
    __builtin_amdgcn_global_load_lds(
        (const __attribute__((address_space(1))) void*)g,
        (__attribute__((address_space(3))) void*)lds, 16, 0, 0);
}

// ---------------------------------------------------------------- fp32 -> bf16 weight convert
__global__ __launch_bounds__(256) void convert_kernel(
    const float* __restrict__ qkv_w, const float* __restrict__ proj_w,
    unsigned short* __restrict__ wbf)
{
    int i = blockIdx.x * 256 + threadIdx.x;            // grid covers 1048576
    float v = (i < 786432) ? qkv_w[i] : proj_w[i - 786432];
    wbf[i] = f2b(v);
}

// ---------------------------------------------------------------- GN stats
__global__ __launch_bounds__(256) void stats_kernel(
    const float* __restrict__ x, float* __restrict__ stats)
{
    int bg = blockIdx.x;           // 64 blocks: b*32+g
    int b = bg >> 5, g = bg & 31;
    const float* xp = x + ((size_t)b * CH + (size_t)g * 16) * NPIX;
    float s = 0.f, ss = 0.f;
    for (int i = threadIdx.x; i < 16 * NPIX; i += 256) {
        float v = xp[i]; s += v; ss += v * v;
    }
    for (int off = 32; off; off >>= 1) {
        s  += __shfl_down(s,  off, 64);
        ss += __shfl_down(ss, off, 64);
    }
    __shared__ float red[2][4];
    int wv = threadIdx.x >> 6;
    if ((threadIdx.x & 63) == 0) { red[0][wv] = s; red[1][wv] = ss; }
    __syncthreads();
    if (threadIdx.x == 0) {
        s  = red[0][0] + red[0][1] + red[0][2] + red[0][3];
        ss = red[1][0] + red[1][1] + red[1][2] + red[1][3];
        const float inv = 1.f / (16 * NPIX);
        float mean = s * inv;
        float var  = ss * inv - mean * mean;
        stats[bg * 2 + 0] = mean;
        stats[bg * 2 + 1] = rsqrtf(var + 1e-6f);
    }
}

// ---------------------------------------------------------------- K/V GEMM (round-0 proven config)
__global__ __launch_bounds__(256) void kv_kernel(
    const float* __restrict__ x,
    const unsigned short* __restrict__ wbf,  // bf16 qkv_w [1536][512]
    const float* __restrict__ bias,
    const float* __restrict__ gamma,
    const float* __restrict__ beta,
    const float* __restrict__ stats,
    unsigned short* __restrict__ K,          // [b][n][c]
    unsigned short* __restrict__ V)          // [b][c][n]
{
    __shared__ unsigned short hn[32][520];
    int b  = blockIdx.y;
    int m0 = blockIdx.x * 32;
    int tid = threadIdx.x;
    {   // stage hn: p = tid&31 (pixel), cg = tid>>5 (channel slot, 8 wide)
        const float* xb = x + (size_t)b * CH * NPIX;
        const float* st = stats + b * 64;
        int p = tid & 31, cg = tid >> 5;
        for (int c0 = 0; c0 < CH; c0 += 8) {
            int c = c0 + cg;
            float mean = st[(c >> 4) * 2 + 0];
            float rstd = st[(c >> 4) * 2 + 1];
            float ga = gamma[c] * rstd;
            float be = beta[c] - mean * ga;
            hn[p][c] = f2b(xb[(size_t)c * NPIX + m0 + p] * ga + be);
        }
    }
    __syncthreads();

    int wv = tid >> 6, lane = tid & 63, ln = lane & 15, quad = lane >> 4;
    #pragma unroll
    for (int nt = 0; nt < 16; nt++) {
        int o = nt * 64 + wv * 16 + ln;            // [0, 1024)
        const unsigned short* bp = wbf + (size_t)(512 + o) * CH + quad * 8;
        bf16x8 wf[16];
        #pragma unroll
        for (int k = 0; k < 16; k++) wf[k] = *(const bf16x8*)(bp + k * 32);
        float bi = bias[512 + o];
        #pragma unroll
        for (int qt = 0; qt < 2; qt++) {
            f32x4 acc = {0.f, 0.f, 0.f, 0.f};
            #pragma unroll
            for (int k = 0; k < 16; k++) {
                bf16x8 a = *(const bf16x8*)(&hn[qt * 16 + ln][quad * 8 + k * 32]);
                acc = __builtin_amdgcn_mfma_f32_16x16x32_bf16(a, wf[k], acc, 0, 0, 0);
            }
            int m = m0 + qt * 16 + quad * 4;
            if (o < 512) {
                #pragma unroll
                for (int r = 0; r < 4; r++)
                    K[((size_t)b * NPIX + m + r) * CH + o] = f2b(acc[r] + bi);
            } else {
                bf16x4 pk;
                #pragma unroll
                for (int r = 0; r < 4; r++) pk[r] = f2b(acc[r] + bi);
                *(bf16x4*)(V + ((size_t)b * CH + o - 512) * NPIX + m) = pk;
            }
        }
    }
}

// ---------------------------------------------------------------- attention (split-K flash)
// 256 blocks, 1/CU. bid&7 = XCD -> (batch, key-split) affinity so each XCD's
// 32 CUs share one 4MB K/V working set (= its L2). 64 queries x 2048 keys per block.
// Partial O (numerator, bf16) + m,l (fp32) to workspace; merge_kernel combines.
__global__ __launch_bounds__(512, 2) void attn_kernel(
    const float* __restrict__ x,
    const unsigned short* __restrict__ qw,   // bf16 qkv_w rows [0,512)
    const float* __restrict__ qb,
    const float* __restrict__ gamma,
    const float* __restrict__ beta,
    const float* __restrict__ stats,
    const unsigned short* __restrict__ Kg,
    const unsigned short* __restrict__ Vg,
    unsigned short* __restrict__ Opart,      // [b][split][4096][512] bf16
    float* __restrict__ ml)                  // [b][split][4096][2] f32
{
    // LDS map (bytes) — regions alias across phases:
    //   [0,      66560)  hn  [64][520] bf16   (live: start .. end of Phase Q)
    //   [66560, 133120)  qls [64][520] bf16   (live: Phase Q .. qf preload)
    //   [0,      65536)  K buf0  (first write: prologue, after barrier1 -> hn dead)
    //   [65536, 131072)  K buf1  (first write: iter0 stage-next, after barrier2 -> qls dead)
    //   [131072,148480)  Sbuf [64][68] f32    (first write iter0, after barrier2)
    //   [148480,157696)  Pbuf [64][72] bf16
    __shared__ __align__(16) char sm[157696];
    unsigned short (*hn)[520]  = (unsigned short(*)[520])(sm);
    unsigned short (*qls)[520] = (unsigned short(*)[520])(sm + 66560);
    char* const Kb0 = sm;
    char* const Kb1 = sm + 65536;
    float (*Sbuf)[68]          = (float(*)[68])(sm + 131072);
    unsigned short (*Pbuf)[72] = (unsigned short(*)[72])(sm + 148480);
    __shared__ float mbuf[64], lbuf[64], abuf[64];

    int bid = blockIdx.x;
    int xcd = bid & 7;
    int b   = xcd >> 2;
    int sp  = (xcd >> 1) & 1;
    int q0  = (((bid >> 3) << 1) | (xcd & 1)) << 6;   // 64-query tile
    int tid = threadIdx.x;
    int wv = tid >> 6, lane = tid & 63, ln = lane & 15, quad = lane >> 4;
    const float* xb = x + (size_t)b * CH * NPIX;
    const unsigned short* K = Kg + ((size_t)b * NPIX + (size_t)sp * SPK) * CH;
    const unsigned short* V = Vg + (size_t)b * CH * NPIX + (size_t)sp * SPK;

    {   // stage hn: p = tid&63 (pixel), cg = tid>>6 (channel slot, 8 wide)
        const float* st = stats + b * 64;
        int p = tid & 63, cg = tid >> 6;
        for (int c0 = 0; c0 < CH; c0 += 8) {
            int c = c0 + cg;
            float mean = st[(c >> 4) * 2 + 0];
            float rstd = st[(c >> 4) * 2 + 1];
            float ga = gamma[c] * rstd;
            float be = beta[c] - mean * ga;
            hn[p][c] = f2b(xb[(size_t)c * NPIX + q0 + p] * ga + be);
        }
    }
    if (tid < 64) { mbuf[tid] = -1e30f; lbuf[tid] = 0.f; }
    __syncthreads();

    // ---- Phase Q: q[64][512]; wave wv computes channels [wv*64,+64)
    #pragma unroll
    for (int nt = 0; nt < 4; nt++) {
        int o = wv * 64 + nt * 16 + ln;
        const unsigned short* bp = qw + (size_t)o * CH + quad * 8;
        bf16x8 wf[16];
        #pragma unroll
        for (int k = 0; k < 16; k++) wf[k] = *(const bf16x8*)(bp + k * 32);
        float bi = qb[o];
        const float scale = 0.04419417382415922f;  // 512^-0.5
        #pragma unroll
        for (int qt = 0; qt < 4; qt++) {
            f32x4 acc = {0.f, 0.f, 0.f, 0.f};
            #pragma unroll
            for (int k = 0; k < 16; k++) {
                bf16x8 a = *(const bf16x8*)(&hn[qt * 16 + ln][quad * 8 + k * 32]);
                acc = __builtin_amdgcn_mfma_f32_16x16x32_bf16(a, wf[k], acc, 0, 0, 0);
            }
            #pragma unroll
            for (int r = 0; r < 4; r++)
                qls[qt * 16 + quad * 4 + r][o] = f2b((acc[r] + bi) * scale);
        }
    }
    // barrier1: hn dead, qls ready (lgkm-only: don't drain any vm queue)
    asm volatile("s_waitcnt lgkmcnt(0)" ::: "memory");
    __builtin_amdgcn_s_barrier();

    // ---- prologue: async-stage K tile 0 into Kb0 (overlaps qf preload)
    {
        const unsigned short* g = K + (size_t)wv * CH + ((lane ^ wv) << 3);
        char* l = Kb0 + wv * 1024;
        #pragma unroll
        for (int is = 0; is < 8; is++)
            gll16(l + is * 8192, g + (size_t)is * 8 * CH);
    }

    // ---- preload q fragments: wave (qs,ks); qs = wv>>1 picks 16 queries
    int qs = wv >> 1, ks = wv & 1;
    bf16x8 qf[16];
    #pragma unroll
    for (int kt = 0; kt < 16; kt++)
        qf[kt] = *(const bf16x8*)(&qls[qs * 16 + ln][quad * 8 + kt * 32]);

    f32x4 O[4][4];   // [qt][ct], D[m=channel][n=query]
    #pragma unroll
    for (int qt = 0; qt < 4; qt++)
        #pragma unroll
        for (int ct = 0; ct < 4; ct++) O[qt][ct] = (f32x4){0.f, 0.f, 0.f, 0.f};

    int c0 = wv * 64;
    // barrier2: qls dead; Kb1/Sbuf writable; stage(0) still in flight (lgkm-only)
    asm volatile("s_waitcnt lgkmcnt(0)" ::: "memory");
    __builtin_amdgcn_s_barrier();

    const int swz = ln & 7;    // staging xor: chunk c holds global chunk c^(row&7)

    // ---- flash loop over 32 key-tiles of 64
    for (int it = 0; it < 32; ++it) {
        int kb = it << 6;
        const char* bufC = (it & 1) ? Kb1 : Kb0;
        char* bufN       = (it & 1) ? Kb0 : Kb1;

        // (a) V register loads for this tile — in flight until PV
        const unsigned short* vp = V + (size_t)(c0 + ln) * NPIX + kb + quad * 8;
        bf16x8 vf[4][2];
        #pragma unroll
        for (int ct = 0; ct < 4; ct++)
            #pragma unroll
            for (int half = 0; half < 2; half++)
                vf[ct][half] = *(const bf16x8*)(vp + (size_t)ct * 16 * NPIX + half * 32);

        // (b) async-stage next K tile (last iter wraps: harmless dummy keeps
        //     the vmcnt accounting uniform)
        {
            int nkb = (kb + 64) & (SPK - 1);
            const unsigned short* g = K + (size_t)(nkb + wv) * CH + ((lane ^ wv) << 3);
            char* l = bufN + wv * 1024;
            #pragma unroll
            for (int is = 0; is < 8; is++)
                gll16(l + is * 8192, g + (size_t)is * 8 * CH);
        }

        // (c) queue = [stage(cur) 8][V 8][stage(next) 8]; oldest-first ⇒
        //     vmcnt(16) guarantees stage(cur) landed.
        asm volatile("s_waitcnt vmcnt(16)" ::: "memory");
        __builtin_amdgcn_s_barrier();

        // (d) S: queries [qs*16,+16) x keys [kb + ks*32,+32): two 16-key subtiles
        #pragma unroll
        for (int h = 0; h < 2; h++) {
            const char* kbase = bufC + (size_t)(ks * 32 + h * 16 + ln) * 1024;
            f32x4 Sa = {0.f, 0.f, 0.f, 0.f}, Sb = {0.f, 0.f, 0.f, 0.f};
            #pragma unroll
            for (int kt = 0; kt < 16; kt += 2) {
                bf16x8 k0 = *(const bf16x8*)(kbase + ((((kt    ) * 4 + quad) ^ swz) << 4));
                bf16x8 k1 = *(const bf16x8*)(kbase + ((((kt + 1) * 4 + quad) ^ swz) << 4));
                Sa = __builtin_amdgcn_mfma_f32_16x16x32_bf16(qf[kt],     k0, Sa, 0, 0, 0);
                Sb = __builtin_amdgcn_mfma_f32_16x16x32_bf16(qf[kt + 1], k1, Sb, 0, 0, 0);
            }
            f32x4 S = Sa + Sb;
            #pragma unroll
            for (int r = 0; r < 4; r++)
                Sbuf[qs * 16 + quad * 4 + r][ks * 32 + h * 16 + ln] = S[r];
        }
        asm volatile("s_waitcnt lgkmcnt(0)" ::: "memory");
        __builtin_amdgcn_s_barrier();

        // (f) online softmax: row r (query) by 8 threads, 8 keys each
        {
            int r = tid >> 3, j = tid & 7;
            f32x4 s0 = *(const f32x4*)(&Sbuf[r][j * 8]);
            f32x4 s1 = *(const f32x4*)(&Sbuf[r][j * 8 + 4]);
            float mx = fmaxf(fmaxf(fmaxf(s0[0], s0[1]), fmaxf(s0[2], s0[3])),
                             fmaxf(fmaxf(s1[0], s1[1]), fmaxf(s1[2], s1[3])));
            #pragma unroll
            for (int off = 1; off < 8; off <<= 1) mx = fmaxf(mx, __shfl_xor(mx, off, 64));
            float mprev = mbuf[r];
            float mnew  = fmaxf(mprev, mx);
            float alpha = __expf(mprev - mnew);
            float e0 = __expf(s0[0] - mnew), e1 = __expf(s0[1] - mnew);
            float e2 = __expf(s0[2] - mnew), e3 = __expf(s0[3] - mnew);
            float e4 = __expf(s1[0] - mnew), e5 = __expf(s1[1] - mnew);
            float e6 = __expf(s1[2] - mnew), e7 = __expf(s1[3] - mnew);
            bf16x8 pk = { (short)f2b(e0), (short)f2b(e1), (short)f2b(e2), (short)f2b(e3),
                          (short)f2b(e4), (short)f2b(e5), (short)f2b(e6), (short)f2b(e7) };
            *(bf16x8*)(&Pbuf[r][j * 8]) = pk;
            float sum = (e0 + e1 + e2 + e3) + (e4 + e5 + e6 + e7);
            #pragma unroll
            for (int off = 1; off < 8; off <<= 1) sum += __shfl_xor(sum, off, 64);
            if (j == 0) { mbuf[r] = mnew; lbuf[r] = lbuf[r] * alpha + sum; abuf[r] = alpha; }
        }
        asm volatile("s_waitcnt lgkmcnt(0)" ::: "memory");
        __builtin_amdgcn_s_barrier();

        // (h) PV: A=v[channel][key], B=P[query][key]; D[channel][query]
        #pragma unroll
        for (int qt = 0; qt < 4; qt++) {
            float al = abuf[qt * 16 + ln];
            #pragma unroll
            for (int ct = 0; ct < 4; ct++) {
                #pragma unroll
                for (int r = 0; r < 4; r++) O[qt][ct][r] *= al;
            }
            #pragma unroll
            for (int half = 0; half < 2; half++) {
                bf16x8 pf = *(const bf16x8*)(&Pbuf[qt * 16 + ln][half * 32 + quad * 8]);
                #pragma unroll
                for (int ct = 0; ct < 4; ct++)
                    O[qt][ct] = __builtin_amdgcn_mfma_f32_16x16x32_bf16(vf[ct][half], pf, O[qt][ct], 0, 0, 0);
            }
        }
    }
    __syncthreads();   // full drain (incl. dummy stage); mbuf/lbuf final

    // ---- store partial O numerators (bf16) + m,l
    unsigned short* Ob = Opart + (((size_t)(b * 2 + sp) * NPIX + q0) * CH);
    #pragma unroll
    for (int qt = 0; qt < 4; qt++) {
        #pragma unroll
        for (int ct = 0; ct < 4; ct++) {
            bf16x4 pk;
            #pragma unroll
            for (int r = 0; r < 4; r++) pk[r] = f2b(O[qt][ct][r]);
            *(bf16x4*)(Ob + (size_t)(qt * 16 + ln) * CH + c0 + ct * 16 + quad * 4) = pk;
        }
    }
    if (tid < 64) {
        size_t i = ((size_t)(b * 2 + sp) * NPIX + q0 + tid) * 2;
        ml[i + 0] = mbuf[tid];
        ml[i + 1] = lbuf[tid];
    }
}

// ---------------------------------------------------------------- merge splits + proj + residual
__global__ __launch_bounds__(512, 2) void merge_kernel(
    const float* __restrict__ x,
    const unsigned short* __restrict__ Opart,
    const float* __restrict__ ml,
    const unsigned short* __restrict__ pw,   // bf16 proj_w [512][512]
    const float* __restrict__ pb,
    float* __restrict__ out)
{
    __shared__ __align__(16) unsigned short ao[32][520];
    int b  = blockIdx.y;
    int q0 = blockIdx.x * 32;
    int tid = threadIdx.x;
    int wv = tid >> 6, lane = tid & 63, ln = lane & 15, quad = lane >> 4;

    {   // combine the two splits: p = tid&31 (pixel), cs = tid>>5 (16 slots)
        int p = tid & 31, cs = tid >> 5;
        int n = q0 + p;
        size_t i0 = ((size_t)(b * 2 + 0) * NPIX + n) * 2;
        size_t i1 = ((size_t)(b * 2 + 1) * NPIX + n) * 2;
        float m0 = ml[i0], l0 = ml[i0 + 1];
        float m1 = ml[i1], l1 = ml[i1 + 1];
        float M  = fmaxf(m0, m1);
        float e0 = __expf(m0 - M), e1 = __expf(m1 - M);
        float den = l0 * e0 + l1 * e1;
        float w0 = e0 / den, w1 = e1 / den;
        const unsigned short* O0 = Opart + ((size_t)(b * 2 + 0) * NPIX + n) * CH;
        const unsigned short* O1 = Opart + ((size_t)(b * 2 + 1) * NPIX + n) * CH;
        #pragma unroll
        for (int k = 0; k < 4; k++) {
            int c = cs * 8 + k * 128;
            bf16x8 a0 = *(const bf16x8*)(O0 + c);
            bf16x8 a1 = *(const bf16x8*)(O1 + c);
            #pragma unroll
            for (int j = 0; j < 8; j++)
                ao[p][c + j] = f2b(b2f((unsigned short)a0[j]) * w0 +
                                   b2f((unsigned short)a1[j]) * w1);
        }
    }
    __syncthreads();

    // ---- proj: out channels [wv*64,+64) + bias + residual (fp32)
    #pragma unroll
    for (int nt = 0; nt < 4; nt++) {
        int o = wv * 64 + nt * 16 + ln;
        const unsigned short* bp = pw + (size_t)o * CH + quad * 8;
        bf16x8 wf[16];
        #pragma unroll
        for (int k = 0; k < 16; k++) wf[k] = *(const bf16x8*)(bp + k * 32);
        float bi = pb[o];
        #pragma unroll
        for (int qt = 0; qt < 2; qt++) {
            f32x4 acc = {0.f, 0.f, 0.f, 0.f};
            #pragma unroll
            for (int k = 0; k < 16; k++) {
                bf16x8 a = *(const bf16x8*)(&ao[qt * 16 + ln][quad * 8 + k * 32]);
                acc = __builtin_amdgcn_mfma_f32_16x16x32_bf16(a, wf[k], acc, 0, 0, 0);
            }
            size_t base = ((size_t)b * CH + o) * NPIX + q0 + qt * 16 + quad * 4;
            f32x4 xin = *(const f32x4*)(x + base);
            f32x4 o4;
            #pragma unroll
            for (int r = 0; r < 4; r++) o4[r] = xin[r] + acc[r] + bi;
            *(f32x4*)(out + base) = o4;
        }
    }
}

// ----------------------------------------------------------------
extern "C" void kernel_launch(void* const* d_in, const int* in_sizes, int n_in,
                              void* d_out, int out_size, void* d_ws, size_t ws_size,
                              hipStream_t stream)
{
    const float* x      = (const float*)d_in[0];
    const float* gn_g   = (const float*)d_in[1];
    const float* gn_b   = (const float*)d_in[2];
    const float* qkv_w  = (const float*)d_in[3];
    const float* qkv_b  = (const float*)d_in[4];
    const float* proj_w = (const float*)d_in[5];
    const float* proj_b = (const float*)d_in[6];
    float* out = (float*)d_out;

    // Workspace (shorts): K 4M | V 4M | wbf 1M | stats 256 | ml 64K | Opart 8M  (~35.8 MB)
    unsigned short* ws  = (unsigned short*)d_ws;
    unsigned short* Kb  = ws;                           // [2][4096][512] bf16
    unsigned short* Vb  = ws + 4u * 1024 * 1024;        // [2][512][4096] bf16
    unsigned short* wbf = ws + 8u * 1024 * 1024;        // qkv_w | proj_w, bf16
    unsigned short* wq  = wbf;
    unsigned short* wp  = wbf + 786432;
    float* stats = (float*)(ws + 9u * 1024 * 1024);              // 512 B
    float* ml    = (float*)(ws + 9u * 1024 * 1024 + 256);        // [2][2][4096][2] f32
    unsigned short* Opart = ws + 9u * 1024 * 1024 + 256 + 65536; // [2][2][4096][512] bf16

    convert_kernel<<<dim3(1048576 / 256), 256, 0, stream>>>(qkv_w, proj_w, wbf);
    stats_kernel  <<<dim3(64), 256, 0, stream>>>(x, stats);
    kv_kernel     <<<dim3(NPIX / 32, BATCH), 256, 0, stream>>>(
        x, wbf, qkv_b, gn_g, gn_b, stats, Kb, Vb);
    attn_kernel   <<<dim3(256), 512, 0, stream>>>(
        x, wq, qkv_b, gn_g, gn_b, stats, Kb, Vb, Opart, ml);
    merge_kernel  <<<dim3(NPIX / 32, BATCH), 512, 0, stream>>>(
        x, Opart, ml, wp, proj_b, out);
}